// Round 1
// baseline (523.049 us; speedup 1.0000x reference)
//
#include <hip/hip_runtime.h>
#include <math.h>

// ---------------------------------------------------------------------------
// XLSTMCell: gates = [x|h] @ W + b  (16384 x 5120 x 2048 GEMM, bf16 MFMA)
// then fused cell update + row-LayerNorm(o_gate) epilogue.
// ws layout (244 MiB needed):
//   A_bf16  [16384][2048]  (x cols 0..1023, h cols 1024..2047)      64 MiB
//   Wt_bf16 [5120][2048]   (W transposed, K-contiguous)             20 MiB
//   gates   [16384][5120]  bf16, activations already applied       160 MiB
// ---------------------------------------------------------------------------

typedef unsigned short u16;
typedef unsigned int   u32;
typedef short  short8 __attribute__((ext_vector_type(8)));
typedef float  f32x4  __attribute__((ext_vector_type(4)));
typedef u16    u16x4  __attribute__((ext_vector_type(4)));
typedef u32    u32x4  __attribute__((ext_vector_type(4)));

#define B_ROWS 16384
#define K_DIM  2048
#define N_DIM  5120
#define H_DIM  1024

__device__ __forceinline__ float b2f(u16 u) {
    u32 v = ((u32)u) << 16;
    return __uint_as_float(v);
}
__device__ __forceinline__ u16 f2b(float f) {   // round-to-nearest-even
    u32 x = __float_as_uint(f);
    u32 r = (x + 0x7fffu + ((x >> 16) & 1u)) >> 16;
    return (u16)r;
}
__device__ __forceinline__ float sigm(float v) {
    return 1.f / (1.f + __expf(-v));
}
__device__ __forceinline__ float tanh_fast(float v) {
    v = fminf(fmaxf(v, -15.f), 15.f);
    float e = __expf(-2.f * v);
    return (1.f - e) / (1.f + e);
}

// ---------------------------------------------------------------------------
// 1) pack [x | h_prev] -> bf16 A [16384][2048]
// ---------------------------------------------------------------------------
__global__ __launch_bounds__(256) void convert_A(const float* __restrict__ x,
                                                 const float* __restrict__ h,
                                                 u16* __restrict__ A) {
    size_t idx = ((size_t)blockIdx.x * 256 + threadIdx.x) * 8;   // element idx
    int row = (int)(idx >> 11);
    int col = (int)(idx & 2047);
    const float* src = (col < 1024) ? (x + (size_t)row * 1024 + col)
                                    : (h + (size_t)row * 1024 + (col - 1024));
    f32x4 v0 = *(const f32x4*)src;
    f32x4 v1 = *(const f32x4*)(src + 4);
    u32x4 w;
    w.x = (u32)f2b(v0.x) | ((u32)f2b(v0.y) << 16);
    w.y = (u32)f2b(v0.z) | ((u32)f2b(v0.w) << 16);
    w.z = (u32)f2b(v1.x) | ((u32)f2b(v1.y) << 16);
    w.w = (u32)f2b(v1.z) | ((u32)f2b(v1.w) << 16);
    *(u32x4*)(A + idx) = w;
}

// ---------------------------------------------------------------------------
// 2) W [2048][5120] f32 -> Wt [5120][2048] bf16 (LDS-tiled transpose)
// ---------------------------------------------------------------------------
__global__ __launch_bounds__(256) void convert_W(const float* __restrict__ W,
                                                 u16* __restrict__ Wt) {
    __shared__ float tile[32][33];
    int tx = threadIdx.x & 31;
    int ty = threadIdx.x >> 5;          // 0..7
    int n0 = blockIdx.x * 32;           // 160 blocks
    int k0 = blockIdx.y * 32;           // 64 blocks
#pragma unroll
    for (int i = 0; i < 4; ++i)
        tile[ty + 8 * i][tx] = W[(size_t)(k0 + ty + 8 * i) * N_DIM + n0 + tx];
    __syncthreads();
#pragma unroll
    for (int i = 0; i < 4; ++i)
        Wt[(size_t)(n0 + ty + 8 * i) * K_DIM + k0 + tx] = f2b(tile[tx][ty + 8 * i]);
}

// ---------------------------------------------------------------------------
// 3) GEMM: gates = act(A @ Wt^T + b), 128x128 tile, BK=64, 4 waves
// ---------------------------------------------------------------------------
#define BM 128
#define BN 128
#define BK 64

__device__ __forceinline__ void gld_lds16(const void* g, void* l) {
    __builtin_amdgcn_global_load_lds(
        (const __attribute__((address_space(1))) void*)g,
        (__attribute__((address_space(3))) void*)l, 16, 0, 0);
}

__global__ __launch_bounds__(256, 2) void gemm_gates(const u16* __restrict__ A,
                                                     const u16* __restrict__ Bt,
                                                     const float* __restrict__ bias,
                                                     u16* __restrict__ gates) {
    __shared__ u16 As[BM * BK];
    __shared__ u16 Bs[BN * BK];

    const int t  = threadIdx.x;
    const int m0 = blockIdx.x * BM;     // 128 blocks
    const int n0 = blockIdx.y * BN;     // 40 blocks
    const int l  = t & 63;
    const int wid = t >> 6;
    const int wm = (wid >> 1) << 6;     // 0 / 64
    const int wn = (wid & 1) << 6;      // 0 / 64
    const int lr = l & 15;
    const int lh = l >> 4;

    f32x4 acc[4][4] = {};

    // staging: thread t loads 16B; linear LDS = row-major [128][64] bf16
    const int sRow = t >> 3;            // 0..31
    const int sK   = (t & 7) * 8;
    const u16* aPtr = A  + (size_t)(m0 + sRow) * K_DIM + sK;
    const u16* bPtr = Bt + (size_t)(n0 + sRow) * K_DIM + sK;

    for (int ktile = 0; ktile < K_DIM / BK; ++ktile) {
#pragma unroll
        for (int it = 0; it < 4; ++it) {
            gld_lds16(aPtr + (size_t)it * 32 * K_DIM, &As[(it * 256 + t) * 8]);
            gld_lds16(bPtr + (size_t)it * 32 * K_DIM, &Bs[(it * 256 + t) * 8]);
        }
        __syncthreads();   // compiler drains vmcnt before barrier
#pragma unroll
        for (int s = 0; s < 2; ++s) {
            short8 af[4], bf[4];
#pragma unroll
            for (int mi = 0; mi < 4; ++mi)
                af[mi] = *(const short8*)&As[(wm + mi * 16 + lr) * BK + s * 32 + lh * 8];
#pragma unroll
            for (int ni = 0; ni < 4; ++ni)
                bf[ni] = *(const short8*)&Bs[(wn + ni * 16 + lr) * BK + s * 32 + lh * 8];
#pragma unroll
            for (int mi = 0; mi < 4; ++mi)
#pragma unroll
                for (int ni = 0; ni < 4; ++ni)
                    acc[mi][ni] = __builtin_amdgcn_mfma_f32_16x16x32_bf16(
                        af[mi], bf[ni], acc[mi][ni], 0, 0, 0);
        }
        __syncthreads();
        aPtr += BK;
        bPtr += BK;
    }

    // epilogue: bias + activation (block's N-tile lies in one gate group)
    const int grp = n0 >> 10;           // 0..4 : f,i,o,c,m
#pragma unroll
    for (int ni = 0; ni < 4; ++ni) {
        int col = n0 + wn + ni * 16 + lr;
        float bv = bias[col];
#pragma unroll
        for (int mi = 0; mi < 4; ++mi) {
#pragma unroll
            for (int j = 0; j < 4; ++j) {
                int row = m0 + wm + mi * 16 + lh * 4 + j;
                float v = acc[mi][ni][j] + bv;
                float g = (grp == 3) ? tanh_fast(v) : sigm(v);
                gates[(size_t)row * N_DIM + col] = f2b(g);
            }
        }
    }
}

// ---------------------------------------------------------------------------
// 4) per-row: LN stats over o, cell update, outputs
// ---------------------------------------------------------------------------
__global__ __launch_bounds__(256) void fuse_out(const u16* __restrict__ gates,
                                                const float* __restrict__ c_prev,
                                                const float* __restrict__ ret,
                                                const float* __restrict__ gamma,
                                                const float* __restrict__ beta,
                                                float* __restrict__ out) {
    const int r = blockIdx.x;
    const int t = threadIdx.x;
    const u16* g = gates + (size_t)r * N_DIM;
    const int j0 = t * 4;

    // o = sigmoid(o_pre) already; LN stats over the row of 1024
    u16x4 ov = *(const u16x4*)(g + 2048 + j0);
    float o0 = b2f(ov.x), o1 = b2f(ov.y), o2 = b2f(ov.z), o3 = b2f(ov.w);
    float s1 = o0 + o1 + o2 + o3;
    float s2 = o0 * o0 + o1 * o1 + o2 * o2 + o3 * o3;
#pragma unroll
    for (int off = 32; off; off >>= 1) {
        s1 += __shfl_xor(s1, off, 64);
        s2 += __shfl_xor(s2, off, 64);
    }
    __shared__ float red[8];
    if ((t & 63) == 0) { red[t >> 6] = s1; red[4 + (t >> 6)] = s2; }
    __syncthreads();
    float S1 = red[0] + red[1] + red[2] + red[3];
    float S2 = red[4] + red[5] + red[6] + red[7];
    float mu   = S1 * (1.f / 1024.f);
    float var  = S2 * (1.f / 1024.f) - mu * mu;
    float rstd = rsqrtf(var + 1e-5f);

    u16x4 fv = *(const u16x4*)(g + j0);
    u16x4 iv = *(const u16x4*)(g + 1024 + j0);
    u16x4 cv = *(const u16x4*)(g + 3072 + j0);
    u16x4 mv = *(const u16x4*)(g + 4096 + j0);
    f32x4 cp = *(const f32x4*)(c_prev + (size_t)r * H_DIM + j0);
    f32x4 rt = *(const f32x4*)(ret + j0);
    f32x4 gm = *(const f32x4*)(gamma + j0);
    f32x4 bt = *(const f32x4*)(beta + j0);

    float of[4] = {o0, o1, o2, o3};
    u16 fa[4] = {fv.x, fv.y, fv.z, fv.w};
    u16 ia[4] = {iv.x, iv.y, iv.z, iv.w};
    u16 ca[4] = {cv.x, cv.y, cv.z, cv.w};
    u16 ma[4] = {mv.x, mv.y, mv.z, mv.w};

    f32x4 hout, cout;
#pragma unroll
    for (int i = 0; i < 4; ++i) {
        float f = b2f(fa[i]), ig = b2f(ia[i]), cc = b2f(ca[i]), m = b2f(ma[i]);
        float cpv = cp[i], rv = rt[i];
        float c1 = f * cpv + ig * cc;
        float c2 = c1 * rv + (1.f - rv) * cpv;
        float cn = m * c2 + (1.f - m) * cpv;
        float ln = (of[i] - mu) * rstd * gm[i] + bt[i];
        float oe = sigm(ln);
        float hn = oe * tanh_fast(cn);
        hout[i] = hn;
        cout[i] = cn;
    }
    *(f32x4*)(out + (size_t)r * H_DIM + j0) = hout;
    *(f32x4*)(out + (size_t)B_ROWS * H_DIM + (size_t)r * H_DIM + j0) = cout;
}

// ---------------------------------------------------------------------------
extern "C" void kernel_launch(void* const* d_in, const int* in_sizes, int n_in,
                              void* d_out, int out_size, void* d_ws, size_t ws_size,
                              hipStream_t stream) {
    const float* x      = (const float*)d_in[0];
    const float* h_prev = (const float*)d_in[1];
    const float* c_prev = (const float*)d_in[2];
    const float* W      = (const float*)d_in[3];
    const float* bias   = (const float*)d_in[4];
    const float* gamma  = (const float*)d_in[5];
    const float* beta   = (const float*)d_in[6];
    const float* ret    = (const float*)d_in[7];
    float* out = (float*)d_out;

    u16* Abuf  = (u16*)d_ws;                             // [16384][2048]
    u16* Wt    = Abuf + (size_t)B_ROWS * K_DIM;          // [5120][2048]
    u16* gates = Wt + (size_t)N_DIM * K_DIM;             // [16384][5120]

    convert_A<<<(B_ROWS * K_DIM / 8) / 256, 256, 0, stream>>>(x, h_prev, Abuf);
    convert_W<<<dim3(N_DIM / 32, K_DIM / 32), 256, 0, stream>>>(W, Wt);
    gemm_gates<<<dim3(B_ROWS / BM, N_DIM / BN), 256, 0, stream>>>(Abuf, Wt, bias, gates);
    fuse_out<<<B_ROWS, 256, 0, stream>>>(gates, c_prev, ret, gamma, beta, out);
}

// Round 2
// 517.885 us; speedup vs baseline: 1.0100x; 1.0100x over previous
//
#include <hip/hip_runtime.h>
#include <math.h>

// ---------------------------------------------------------------------------
// XLSTMCell: gates = [x|h] @ W + b  (16384 x 5120 x 2048 GEMM, bf16 MFMA)
// GEMM: 256x256 tile, BK=32, 4-deep LDS ring, counted vmcnt(8), 1 barrier/tile
// ws layout: A_bf16[16384][2048] | Wt_bf16[5120][2048] | gates[16384][5120]
// ---------------------------------------------------------------------------

typedef unsigned short u16;
typedef unsigned int   u32;
typedef short  short8 __attribute__((ext_vector_type(8)));
typedef float  f32x4  __attribute__((ext_vector_type(4)));
typedef u16    u16x4  __attribute__((ext_vector_type(4)));
typedef u32    u32x4  __attribute__((ext_vector_type(4)));

#define B_ROWS 16384
#define K_DIM  2048
#define N_DIM  5120
#define H_DIM  1024

__device__ __forceinline__ float b2f(u16 u) {
    u32 v = ((u32)u) << 16;
    return __uint_as_float(v);
}
__device__ __forceinline__ u16 f2b(float f) {   // round-to-nearest-even
    u32 x = __float_as_uint(f);
    u32 r = (x + 0x7fffu + ((x >> 16) & 1u)) >> 16;
    return (u16)r;
}
__device__ __forceinline__ float sigm(float v) {
    return 1.f / (1.f + __expf(-v));
}
__device__ __forceinline__ float tanh_fast(float v) {
    v = fminf(fmaxf(v, -15.f), 15.f);
    float e = __expf(-2.f * v);
    return (1.f - e) / (1.f + e);
}

// ---------------------------------------------------------------------------
// 1) pack [x | h_prev] -> bf16 A [16384][2048]
// ---------------------------------------------------------------------------
__global__ __launch_bounds__(256) void convert_A(const float* __restrict__ x,
                                                 const float* __restrict__ h,
                                                 u16* __restrict__ A) {
    size_t idx = ((size_t)blockIdx.x * 256 + threadIdx.x) * 8;   // element idx
    int row = (int)(idx >> 11);
    int col = (int)(idx & 2047);
    const float* src = (col < 1024) ? (x + (size_t)row * 1024 + col)
                                    : (h + (size_t)row * 1024 + (col - 1024));
    f32x4 v0 = *(const f32x4*)src;
    f32x4 v1 = *(const f32x4*)(src + 4);
    u32x4 w;
    w.x = (u32)f2b(v0.x) | ((u32)f2b(v0.y) << 16);
    w.y = (u32)f2b(v0.z) | ((u32)f2b(v0.w) << 16);
    w.z = (u32)f2b(v1.x) | ((u32)f2b(v1.y) << 16);
    w.w = (u32)f2b(v1.z) | ((u32)f2b(v1.w) << 16);
    *(u32x4*)(A + idx) = w;
}

// ---------------------------------------------------------------------------
// 2) W [2048][5120] f32 -> Wt [5120][2048] bf16 (LDS-tiled transpose)
// ---------------------------------------------------------------------------
__global__ __launch_bounds__(256) void convert_W(const float* __restrict__ W,
                                                 u16* __restrict__ Wt) {
    __shared__ float tile[32][33];
    int tx = threadIdx.x & 31;
    int ty = threadIdx.x >> 5;          // 0..7
    int n0 = blockIdx.x * 32;           // 160 blocks
    int k0 = blockIdx.y * 32;           // 64 blocks
#pragma unroll
    for (int i = 0; i < 4; ++i)
        tile[ty + 8 * i][tx] = W[(size_t)(k0 + ty + 8 * i) * N_DIM + n0 + tx];
    __syncthreads();
#pragma unroll
    for (int i = 0; i < 4; ++i)
        Wt[(size_t)(n0 + ty + 8 * i) * K_DIM + k0 + tx] = f2b(tile[tx][ty + 8 * i]);
}

// ---------------------------------------------------------------------------
// 3) GEMM: gates = act(A @ Wt^T + b)
//    256x256 tile, BK=32, 512 thr (8 waves 2Mx4N), 4-buf LDS ring.
//    Ring proof: tile t+3 -> buf (t+3)&3, last read at iter t-1; every wave's
//    ds_reads complete before its iter-(t-1) barrier (lgkmcnt before MFMA),
//    and stage issues happen after that barrier => no WAR race.
//    vmcnt(8): after the wait, only tiles t+2,t+3 (4 instr each) may be
//    outstanding => tile t+1 is fully in LDS before its ds_reads.
// ---------------------------------------------------------------------------
#define BK 32
#define NBUF 4

__device__ __forceinline__ void gld_lds16(const void* g, void* l) {
    __builtin_amdgcn_global_load_lds(
        (const __attribute__((address_space(1))) void*)g,
        (__attribute__((address_space(3))) void*)l, 16, 0, 0);
}

__global__ __launch_bounds__(512, 2) void gemm_gates(const u16* __restrict__ A,
                                                     const u16* __restrict__ Bt,
                                                     const float* __restrict__ bias,
                                                     u16* __restrict__ gates) {
    __shared__ u16 lds[NBUF][2][256 * BK];   // 4 x 2 x 16 KiB = 128 KiB

    const int t = threadIdx.x;
    // T1: bijective XCD swizzle (nwg=1280, 1280%8==0). Consecutive ids within
    // an XCD chunk share the B panel -> L2 locality.
    const int bid = blockIdx.x;
    const int swz = (bid & 7) * 160 + (bid >> 3);
    const int m0 = (swz & 63) << 8;          // 64 M-blocks
    const int n0 = (swz >> 6) << 8;          // 20 N-blocks

    const int l   = t & 63;
    const int wid = t >> 6;
    const int wm  = (wid >> 2) << 7;         // 0 / 128
    const int wn  = (wid & 3) << 6;          // 0..192
    const int lr  = l & 15;
    const int lh  = l >> 4;

    f32x4 acc[8][4] = {};

    // staging: thread t -> LDS u16 offset t*8 (+4096 for j=1); linear dest.
    const int sRow = t >> 2;                 // 0..127 (+128 for j=1)
    const int sCol = (t & 3) * 8;
    const u16* aBase = A  + (size_t)(m0 + sRow) * K_DIM + sCol;
    const u16* bBase = Bt + (size_t)(n0 + sRow) * K_DIM + sCol;
    const int ldsOff = t * 8;

#define STAGE(kt, buf)                                                        \
    do {                                                                      \
        const u16* a_ = aBase + (kt) * BK;                                    \
        const u16* b_ = bBase + (kt) * BK;                                    \
        gld_lds16(a_,                        &lds[buf][0][ldsOff]);           \
        gld_lds16(a_ + (size_t)128 * K_DIM,  &lds[buf][0][ldsOff + 4096]);    \
        gld_lds16(b_,                        &lds[buf][1][ldsOff]);           \
        gld_lds16(b_ + (size_t)128 * K_DIM,  &lds[buf][1][ldsOff + 4096]);    \
    } while (0)

    STAGE(0, 0);
    STAGE(1, 1);
    STAGE(2, 2);
    __builtin_amdgcn_sched_barrier(0);
    asm volatile("s_waitcnt vmcnt(8)" ::: "memory");   // tile 0 landed
    __builtin_amdgcn_s_barrier();
    __builtin_amdgcn_sched_barrier(0);

    const int NKT = K_DIM / BK;              // 64
    for (int kt = 0; kt < NKT; ++kt) {
        const int buf = kt & (NBUF - 1);
        if (kt + 3 < NKT) STAGE(kt + 3, (kt + 3) & (NBUF - 1));

        const u16* As = lds[buf][0];
        const u16* Bs = lds[buf][1];
        short8 af[8], bf[4];
#pragma unroll
        for (int ni = 0; ni < 4; ++ni)
            bf[ni] = *(const short8*)&Bs[(wn + ni * 16 + lr) * BK + lh * 8];
#pragma unroll
        for (int mi = 0; mi < 8; ++mi)
            af[mi] = *(const short8*)&As[(wm + mi * 16 + lr) * BK + lh * 8];

        __builtin_amdgcn_s_setprio(1);
#pragma unroll
        for (int mi = 0; mi < 8; ++mi)
#pragma unroll
            for (int ni = 0; ni < 4; ++ni)
                acc[mi][ni] = __builtin_amdgcn_mfma_f32_16x16x32_bf16(
                    af[mi], bf[ni], acc[mi][ni], 0, 0, 0);
        __builtin_amdgcn_s_setprio(0);

        __builtin_amdgcn_sched_barrier(0);
        if (kt < NKT - 3) {
            asm volatile("s_waitcnt vmcnt(8)" ::: "memory");  // tile kt+1 in
        } else {
            asm volatile("s_waitcnt vmcnt(0)" ::: "memory");  // epilogue drain
        }
        __builtin_amdgcn_s_barrier();
        __builtin_amdgcn_sched_barrier(0);
    }
#undef STAGE

    // epilogue: bias + activation (block's N-tile lies in one gate group)
    const int grp = n0 >> 10;                // 0..4 : f,i,o,c,m
#pragma unroll
    for (int ni = 0; ni < 4; ++ni) {
        int col = n0 + wn + ni * 16 + lr;
        float bv = bias[col];
#pragma unroll
        for (int mi = 0; mi < 8; ++mi) {
#pragma unroll
            for (int j = 0; j < 4; ++j) {
                int row = m0 + wm + mi * 16 + lh * 4 + j;
                float v = acc[mi][ni][j] + bv;
                float g = (grp == 3) ? tanh_fast(v) : sigm(v);
                gates[(size_t)row * N_DIM + col] = f2b(g);
            }
        }
    }
}

// ---------------------------------------------------------------------------
// 4) per-row: LN stats over o, cell update, outputs
// ---------------------------------------------------------------------------
__global__ __launch_bounds__(256) void fuse_out(const u16* __restrict__ gates,
                                                const float* __restrict__ c_prev,
                                                const float* __restrict__ ret,
                                                const float* __restrict__ gamma,
                                                const float* __restrict__ beta,
                                                float* __restrict__ out) {
    const int r = blockIdx.x;
    const int t = threadIdx.x;
    const u16* g = gates + (size_t)r * N_DIM;
    const int j0 = t * 4;

    // o = sigmoid(o_pre) already; LN stats over the row of 1024
    u16x4 ov = *(const u16x4*)(g + 2048 + j0);
    float o0 = b2f(ov.x), o1 = b2f(ov.y), o2 = b2f(ov.z), o3 = b2f(ov.w);
    float s1 = o0 + o1 + o2 + o3;
    float s2 = o0 * o0 + o1 * o1 + o2 * o2 + o3 * o3;
#pragma unroll
    for (int off = 32; off; off >>= 1) {
        s1 += __shfl_xor(s1, off, 64);
        s2 += __shfl_xor(s2, off, 64);
    }
    __shared__ float red[8];
    if ((t & 63) == 0) { red[t >> 6] = s1; red[4 + (t >> 6)] = s2; }
    __syncthreads();
    float S1 = red[0] + red[1] + red[2] + red[3];
    float S2 = red[4] + red[5] + red[6] + red[7];
    float mu   = S1 * (1.f / 1024.f);
    float var  = S2 * (1.f / 1024.f) - mu * mu;
    float rstd = rsqrtf(var + 1e-5f);

    u16x4 fv = *(const u16x4*)(g + j0);
    u16x4 iv = *(const u16x4*)(g + 1024 + j0);
    u16x4 cv = *(const u16x4*)(g + 3072 + j0);
    u16x4 mv = *(const u16x4*)(g + 4096 + j0);
    f32x4 cp = *(const f32x4*)(c_prev + (size_t)r * H_DIM + j0);
    f32x4 rt = *(const f32x4*)(ret + j0);
    f32x4 gm = *(const f32x4*)(gamma + j0);
    f32x4 bt = *(const f32x4*)(beta + j0);

    float of[4] = {o0, o1, o2, o3};
    u16 fa[4] = {fv.x, fv.y, fv.z, fv.w};
    u16 ia[4] = {iv.x, iv.y, iv.z, iv.w};
    u16 ca[4] = {cv.x, cv.y, cv.z, cv.w};
    u16 ma[4] = {mv.x, mv.y, mv.z, mv.w};

    f32x4 hout, cout;
#pragma unroll
    for (int i = 0; i < 4; ++i) {
        float f = b2f(fa[i]), ig = b2f(ia[i]), cc = b2f(ca[i]), m = b2f(ma[i]);
        float cpv = cp[i], rv = rt[i];
        float c1 = f * cpv + ig * cc;
        float c2 = c1 * rv + (1.f - rv) * cpv;
        float cn = m * c2 + (1.f - m) * cpv;
        float ln = (of[i] - mu) * rstd * gm[i] + bt[i];
        float oe = sigm(ln);
        float hn = oe * tanh_fast(cn);
        hout[i] = hn;
        cout[i] = cn;
    }
    *(f32x4*)(out + (size_t)r * H_DIM + j0) = hout;
    *(f32x4*)(out + (size_t)B_ROWS * H_DIM + (size_t)r * H_DIM + j0) = cout;
}

// ---------------------------------------------------------------------------
extern "C" void kernel_launch(void* const* d_in, const int* in_sizes, int n_in,
                              void* d_out, int out_size, void* d_ws, size_t ws_size,
                              hipStream_t stream) {
    const float* x      = (const float*)d_in[0];
    const float* h_prev = (const float*)d_in[1];
    const float* c_prev = (const float*)d_in[2];
    const float* W      = (const float*)d_in[3];
    const float* bias   = (const float*)d_in[4];
    const float* gamma  = (const float*)d_in[5];
    const float* beta   = (const float*)d_in[6];
    const float* ret    = (const float*)d_in[7];
    float* out = (float*)d_out;

    u16* Abuf  = (u16*)d_ws;                             // [16384][2048]
    u16* Wt    = Abuf + (size_t)B_ROWS * K_DIM;          // [5120][2048]
    u16* gates = Wt + (size_t)N_DIM * K_DIM;             // [16384][5120]

    convert_A<<<(B_ROWS * K_DIM / 8) / 256, 256, 0, stream>>>(x, h_prev, Abuf);
    convert_W<<<dim3(N_DIM / 32, K_DIM / 32), 256, 0, stream>>>(W, Wt);
    gemm_gates<<<(B_ROWS / 256) * (N_DIM / 256), 512, 0, stream>>>(Abuf, Wt, bias, gates);
    fuse_out<<<B_ROWS, 256, 0, stream>>>(gates, c_prev, ret, gamma, beta, out);
}

// Round 4
// 499.821 us; speedup vs baseline: 1.0465x; 1.0361x over previous
//
#include <hip/hip_runtime.h>
#include <math.h>

// ---------------------------------------------------------------------------
// XLSTMCell: gates = [x|h] @ W + b  (16384 x 5120 x 2048 GEMM, bf16 MFMA)
// GEMM: 256x256 tile, BK=64, depth-2 LDS ring, counted vmcnt(8), 1 barrier
// pair per K-tile. A/Wt are PRE-SWIZZLED in ws (granule g of each row's
// 64-elem K-window stored at slot g^(row&7)) so linear global_load_lds
// staging + XOR'd ds_read addresses give conflict-free b128 fragment reads.
// ws layout: A_bf16[16384][2048] | Wt_bf16[5120][2048] | gates[16384][5120]
// ---------------------------------------------------------------------------

typedef unsigned short u16;
typedef unsigned int   u32;
typedef short  short8 __attribute__((ext_vector_type(8)));
typedef float  f32x4  __attribute__((ext_vector_type(4)));
typedef u16    u16x4  __attribute__((ext_vector_type(4)));
typedef u32    u32x4  __attribute__((ext_vector_type(4)));

#define B_ROWS 16384
#define K_DIM  2048
#define N_DIM  5120
#define H_DIM  1024

__device__ __forceinline__ float b2f(u16 u) {
    u32 v = ((u32)u) << 16;
    return __uint_as_float(v);
}
__device__ __forceinline__ u16 f2b(float f) {   // round-to-nearest-even
    u32 x = __float_as_uint(f);
    u32 r = (x + 0x7fffu + ((x >> 16) & 1u)) >> 16;
    return (u16)r;
}
__device__ __forceinline__ float sigm(float v) {
    return 1.f / (1.f + __expf(-v));
}
__device__ __forceinline__ float tanh_fast(float v) {
    v = fminf(fmaxf(v, -15.f), 15.f);
    float e = __expf(-2.f * v);
    return (1.f - e) / (1.f + e);
}

// ---------------------------------------------------------------------------
// 1) pack [x | h_prev] -> bf16 A [16384][2048], PRE-SWIZZLED:
//    output granule slot s (8 u16) of each 64-elem K-window of row r holds
//    source granule s ^ (r & 7) of that window.
// ---------------------------------------------------------------------------
__global__ __launch_bounds__(256) void convert_A(const float* __restrict__ x,
                                                 const float* __restrict__ h,
                                                 u16* __restrict__ A) {
    size_t idx = ((size_t)blockIdx.x * 256 + threadIdx.x) * 8;   // out elem idx
    int row = (int)(idx >> 11);
    int col = (int)(idx & 2047);                 // granule-aligned (col%8==0)
    int srcCol = (col & ~63) | (((((col >> 3) & 7) ^ (row & 7))) << 3);
    const float* src = (srcCol < 1024) ? (x + (size_t)row * 1024 + srcCol)
                                       : (h + (size_t)row * 1024 + (srcCol - 1024));
    f32x4 v0 = *(const f32x4*)src;
    f32x4 v1 = *(const f32x4*)(src + 4);
    u32x4 w;
    w.x = (u32)f2b(v0.x) | ((u32)f2b(v0.y) << 16);
    w.y = (u32)f2b(v0.z) | ((u32)f2b(v0.w) << 16);
    w.z = (u32)f2b(v1.x) | ((u32)f2b(v1.y) << 16);
    w.w = (u32)f2b(v1.z) | ((u32)f2b(v1.w) << 16);
    *(u32x4*)(A + idx) = w;
}

// ---------------------------------------------------------------------------
// 2) W [2048][5120] f32 -> Wt [5120][2048] bf16, transposed + PRE-SWIZZLED
//    (same granule rule, keyed by n-row & 7). 64-wide k tiles so the swizzle
//    window stays inside the tile.
// ---------------------------------------------------------------------------
__global__ __launch_bounds__(256) void convert_W(const float* __restrict__ W,
                                                 u16* __restrict__ Wt) {
    __shared__ float tile[64][33];      // [k][n]
    const int t  = threadIdx.x;
    const int tx = t & 31;              // n
    const int ty = t >> 5;              // 0..7 (k)
    const int n0 = blockIdx.x * 32;     // 160 blocks
    const int k0 = blockIdx.y * 64;     // 32 blocks
#pragma unroll
    for (int i = 0; i < 8; ++i)
        tile[ty + 8 * i][tx] = W[(size_t)(k0 + ty + 8 * i) * N_DIM + n0 + tx];
    __syncthreads();
    const int n = t >> 3;               // 0..31
    const int s = t & 7;                // output granule slot
    const int g = s ^ (n & 7);          // source granule ((n0+n)&7 == n&7)
    u32x4 w;
    w.x = (u32)f2b(tile[g * 8 + 0][n]) | ((u32)f2b(tile[g * 8 + 1][n]) << 16);
    w.y = (u32)f2b(tile[g * 8 + 2][n]) | ((u32)f2b(tile[g * 8 + 3][n]) << 16);
    w.z = (u32)f2b(tile[g * 8 + 4][n]) | ((u32)f2b(tile[g * 8 + 5][n]) << 16);
    w.w = (u32)f2b(tile[g * 8 + 6][n]) | ((u32)f2b(tile[g * 8 + 7][n]) << 16);
    *(u32x4*)(Wt + (size_t)(n0 + n) * K_DIM + k0 + s * 8) = w;
}

// ---------------------------------------------------------------------------
// 3) GEMM: 256x256 tile, BK=64, 512 thr (8 waves 2Mx4N), depth-2 ring.
//    Per K-tile: STAGE(kt+1) -> vmcnt(8) (=just-issued; all older landed)
//    -> barrier -> ds_reads+MFMA -> barrier. WAR on buf^1 safe: last read one
//    iteration ago, reads complete before that iteration's closing barrier
//    (compiler lgkmcnt before MFMA use), stage issued after it.
// ---------------------------------------------------------------------------
#define BK 64

__device__ __forceinline__ void gld_lds16(const void* g, void* l) {
    __builtin_amdgcn_global_load_lds(
        (const __attribute__((address_space(1))) void*)g,
        (__attribute__((address_space(3))) void*)l, 16, 0, 0);
}

__global__ __launch_bounds__(512, 2) void gemm_gates(const u16* __restrict__ A,
                                                     const u16* __restrict__ Bt,
                                                     const float* __restrict__ bias,
                                                     u16* __restrict__ gates) {
    __shared__ u16 lds[2][2][256 * BK];   // [buf][A|B][256 rows x 64] = 128 KiB

    const int t = threadIdx.x;
    // T1: bijective XCD swizzle (nwg = 1280, 1280 % 8 == 0)
    const int bid = blockIdx.x;
    const int swz = (bid & 7) * 160 + (bid >> 3);
    const int m0 = (swz & 63) << 8;       // 64 M-blocks
    const int n0 = (swz >> 6) << 8;       // 20 N-blocks

    const int l   = t & 63;
    const int wid = t >> 6;
    const int wr  = wid >> 2;             // 0/1  (M)
    const int wc  = wid & 3;              // 0..3 (N)
    const int lr  = l & 15;
    const int lh  = l >> 4;
    const int z   = lr & 7;
    const int sA0 = (lh ^ z) * 8;         // sk=0 granule slot offset (u16)
                                          // sk=1: sA0 ^ 32

    // staging: thread t copies granule (row sRow, slot t&7) of each 64-row
    // stripe; LDS dest = linear (uniform base + lane*16B).
    const int sRow = t >> 3;              // 0..63
    const int sOff = (t & 7) * 8;
    const u16* aBase = A  + (size_t)(m0 + sRow) * K_DIM + sOff;
    const u16* bBase = Bt + (size_t)(n0 + sRow) * K_DIM + sOff;
    const int dOff = t * 8;               // u16; + i*4096 per stripe

    f32x4 acc[8][4] = {};

#define STAGE(kt, buf) do {                                                   \
    _Pragma("unroll") for (int i = 0; i < 4; ++i) {                           \
        gld_lds16(aBase + (size_t)(i * 64) * K_DIM + (kt) * BK,               \
                  &lds[buf][0][dOff + i * 4096]);                             \
        gld_lds16(bBase + (size_t)(i * 64) * K_DIM + (kt) * BK,               \
                  &lds[buf][1][dOff + i * 4096]);                             \
    }                                                                         \
} while (0)

    STAGE(0, 0);

#pragma unroll 1
    for (int kt = 0; kt < 32; ++kt) {
        const int cur = kt & 1;
        if (kt < 31) {
            STAGE(kt + 1, cur ^ 1);
            __builtin_amdgcn_sched_barrier(0);
            asm volatile("s_waitcnt vmcnt(8)" ::: "memory");
        } else {
            __builtin_amdgcn_sched_barrier(0);
            asm volatile("s_waitcnt vmcnt(0)" ::: "memory");
        }
        asm volatile("s_barrier" ::: "memory");
        __builtin_amdgcn_sched_barrier(0);

        const u16* As = lds[cur][0];
        const u16* Bs = lds[cur][1];
        short8 bf[4][2], af[4][2];
#pragma unroll
        for (int ni = 0; ni < 4; ++ni) {
            const int u = (wc * 64 + ni * 16 + lr) * BK;
            bf[ni][0] = *(const short8*)&Bs[u + sA0];
            bf[ni][1] = *(const short8*)&Bs[u + (sA0 ^ 32)];
        }
#pragma unroll
        for (int q = 0; q < 2; ++q) {
#pragma unroll
            for (int m = 0; m < 4; ++m) {
                const int u = (wr * 128 + q * 64 + m * 16 + lr) * BK;
                af[m][0] = *(const short8*)&As[u + sA0];
                af[m][1] = *(const short8*)&As[u + (sA0 ^ 32)];
            }
            __builtin_amdgcn_s_setprio(1);
#pragma unroll
            for (int sk = 0; sk < 2; ++sk)
#pragma unroll
                for (int m = 0; m < 4; ++m)
#pragma unroll
                    for (int ni = 0; ni < 4; ++ni)
                        acc[q * 4 + m][ni] = __builtin_amdgcn_mfma_f32_16x16x32_bf16(
                            af[m][sk], bf[ni][sk], acc[q * 4 + m][ni], 0, 0, 0);
            __builtin_amdgcn_s_setprio(0);
        }

        __builtin_amdgcn_sched_barrier(0);
        asm volatile("s_barrier" ::: "memory");
        __builtin_amdgcn_sched_barrier(0);
    }
#undef STAGE

    // epilogue: bias + activation (block's N-tile lies in one gate group)
    const int grp = n0 >> 10;             // 0..4 : f,i,o,c,m
#pragma unroll
    for (int ni = 0; ni < 4; ++ni) {
        int col = n0 + wc * 64 + ni * 16 + lr;
        float bv = bias[col];
#pragma unroll
        for (int q = 0; q < 2; ++q) {
#pragma unroll
            for (int m = 0; m < 4; ++m) {
#pragma unroll
                for (int j = 0; j < 4; ++j) {
                    int row = m0 + wr * 128 + q * 64 + m * 16 + lh * 4 + j;
                    float v = acc[q * 4 + m][ni][j] + bv;
                    float g = (grp == 3) ? tanh_fast(v) : sigm(v);
                    gates[(size_t)row * N_DIM + col] = f2b(g);
                }
            }
        }
    }
}

// ---------------------------------------------------------------------------
// 4) per-row: LN stats over o, cell update, outputs
// ---------------------------------------------------------------------------
__global__ __launch_bounds__(256) void fuse_out(const u16* __restrict__ gates,
                                                const float* __restrict__ c_prev,
                                                const float* __restrict__ ret,
                                                const float* __restrict__ gamma,
                                                const float* __restrict__ beta,
                                                float* __restrict__ out) {
    const int r = blockIdx.x;
    const int t = threadIdx.x;
    const u16* g = gates + (size_t)r * N_DIM;
    const int j0 = t * 4;

    // o = sigmoid(o_pre) already; LN stats over the row of 1024
    u16x4 ov = *(const u16x4*)(g + 2048 + j0);
    float o0 = b2f(ov.x), o1 = b2f(ov.y), o2 = b2f(ov.z), o3 = b2f(ov.w);
    float s1 = o0 + o1 + o2 + o3;
    float s2 = o0 * o0 + o1 * o1 + o2 * o2 + o3 * o3;
#pragma unroll
    for (int off = 32; off; off >>= 1) {
        s1 += __shfl_xor(s1, off, 64);
        s2 += __shfl_xor(s2, off, 64);
    }
    __shared__ float red[8];
    if ((t & 63) == 0) { red[t >> 6] = s1; red[4 + (t >> 6)] = s2; }
    __syncthreads();
    float S1 = red[0] + red[1] + red[2] + red[3];
    float S2 = red[4] + red[5] + red[6] + red[7];
    float mu   = S1 * (1.f / 1024.f);
    float var  = S2 * (1.f / 1024.f) - mu * mu;
    float rstd = rsqrtf(var + 1e-5f);

    u16x4 fv = *(const u16x4*)(g + j0);
    u16x4 iv = *(const u16x4*)(g + 1024 + j0);
    u16x4 cv = *(const u16x4*)(g + 3072 + j0);
    u16x4 mv = *(const u16x4*)(g + 4096 + j0);
    f32x4 cp = *(const f32x4*)(c_prev + (size_t)r * H_DIM + j0);
    f32x4 rt = *(const f32x4*)(ret + j0);
    f32x4 gm = *(const f32x4*)(gamma + j0);
    f32x4 bt = *(const f32x4*)(beta + j0);

    float of[4] = {o0, o1, o2, o3};
    u16 fa[4] = {fv.x, fv.y, fv.z, fv.w};
    u16 ia[4] = {iv.x, iv.y, iv.z, iv.w};
    u16 ca[4] = {cv.x, cv.y, cv.z, cv.w};
    u16 ma[4] = {mv.x, mv.y, mv.z, mv.w};

    f32x4 hout, cout;
#pragma unroll
    for (int i = 0; i < 4; ++i) {
        float f = b2f(fa[i]), ig = b2f(ia[i]), cc = b2f(ca[i]), m = b2f(ma[i]);
        float cpv = cp[i], rv = rt[i];
        float c1 = f * cpv + ig * cc;
        float c2 = c1 * rv + (1.f - rv) * cpv;
        float cn = m * c2 + (1.f - m) * cpv;
        float ln = (of[i] - mu) * rstd * gm[i] + bt[i];
        float oe = sigm(ln);
        float hn = oe * tanh_fast(cn);
        hout[i] = hn;
        cout[i] = cn;
    }
    *(f32x4*)(out + (size_t)r * H_DIM + j0) = hout;
    *(f32x4*)(out + (size_t)B_ROWS * H_DIM + (size_t)r * H_DIM + j0) = cout;
}

// ---------------------------------------------------------------------------
extern "C" void kernel_launch(void* const* d_in, const int* in_sizes, int n_in,
                              void* d_out, int out_size, void* d_ws, size_t ws_size,
                              hipStream_t stream) {
    const float* x      = (const float*)d_in[0];
    const float* h_prev = (const float*)d_in[1];
    const float* c_prev = (const float*)d_in[2];
    const float* W      = (const float*)d_in[3];
    const float* bias   = (const float*)d_in[4];
    const float* gamma  = (const float*)d_in[5];
    const float* beta   = (const float*)d_in[6];
    const float* ret    = (const float*)d_in[7];
    float* out = (float*)d_out;

    u16* Abuf  = (u16*)d_ws;                             // [16384][2048]
    u16* Wt    = Abuf + (size_t)B_ROWS * K_DIM;          // [5120][2048]
    u16* gates = Wt + (size_t)N_DIM * K_DIM;             // [16384][5120]

    convert_A<<<(B_ROWS * K_DIM / 8) / 256, 256, 0, stream>>>(x, h_prev, Abuf);
    convert_W<<<dim3(N_DIM / 32, K_DIM / 64), 256, 0, stream>>>(W, Wt);
    gemm_gates<<<(B_ROWS / 256) * (N_DIM / 256), 512, 0, stream>>>(Abuf, Wt, bias, gates);
    fuse_out<<<B_ROWS, 256, 0, stream>>>(gates, c_prev, ret, gamma, beta, out);
}

// Round 5
// 486.682 us; speedup vs baseline: 1.0747x; 1.0270x over previous
//
#include <hip/hip_runtime.h>
#include <math.h>

// ---------------------------------------------------------------------------
// XLSTMCell: gates = [x|h] @ W + b  (16384 x 5120 x 2048 GEMM, bf16 MFMA)
// GEMM: 256x256 tile, BK=64, 8-phase interleaved schedule (m201 structure):
// per K-tile 4 phases of {ds_read one unit | stage one unit | barrier |
// lgkmcnt(0) | 16 MFMA | vmcnt(4) (P1/P2/P4) | barrier}. LDS units are
// quadrant-interleaved (A by row-bit6, B by n-bit5) so each phase touches
// exactly one 16 KiB unit. A/Wt PRE-SWIZZLED in global (granule g of each
// 64-col window at slot g^(row&7)) -> linear global_load_lds staging +
// XOR'd ds_read = conflict-free b128 (verified R4: 0 conflicts).
// FIFO-vmcnt proof: stage order A0',B0',B1',A1'; vmcnt(4) guards force the
// exact unit needed by the next phase to have landed (see comments).
// ws layout: A_bf16[16384][2048] | Wt_bf16[5120][2048] | gates[16384][5120]
// ---------------------------------------------------------------------------

typedef unsigned short u16;
typedef unsigned int   u32;
typedef short  short8 __attribute__((ext_vector_type(8)));
typedef float  f32x4  __attribute__((ext_vector_type(4)));
typedef u16    u16x4  __attribute__((ext_vector_type(4)));
typedef u32    u32x4  __attribute__((ext_vector_type(4)));

#define B_ROWS 16384
#define K_DIM  2048
#define N_DIM  5120
#define H_DIM  1024

__device__ __forceinline__ float b2f(u16 u) {
    u32 v = ((u32)u) << 16;
    return __uint_as_float(v);
}
__device__ __forceinline__ u16 f2b(float f) {   // round-to-nearest-even
    u32 x = __float_as_uint(f);
    u32 r = (x + 0x7fffu + ((x >> 16) & 1u)) >> 16;
    return (u16)r;
}
__device__ __forceinline__ float sigm(float v) {
    return 1.f / (1.f + __expf(-v));
}
__device__ __forceinline__ float tanh_fast(float v) {
    v = fminf(fmaxf(v, -15.f), 15.f);
    float e = __expf(-2.f * v);
    return (1.f - e) / (1.f + e);
}

// ---------------------------------------------------------------------------
// 1) pack [x | h_prev] -> bf16 A [16384][2048], PRE-SWIZZLED:
//    granule slot s of each 64-elem K-window of row r holds granule s^(r&7).
// ---------------------------------------------------------------------------
__global__ __launch_bounds__(256) void convert_A(const float* __restrict__ x,
                                                 const float* __restrict__ h,
                                                 u16* __restrict__ A) {
    size_t idx = ((size_t)blockIdx.x * 256 + threadIdx.x) * 8;   // out elem idx
    int row = (int)(idx >> 11);
    int col = (int)(idx & 2047);                 // granule-aligned (col%8==0)
    int srcCol = (col & ~63) | (((((col >> 3) & 7) ^ (row & 7))) << 3);
    const float* src = (srcCol < 1024) ? (x + (size_t)row * 1024 + srcCol)
                                       : (h + (size_t)row * 1024 + (srcCol - 1024));
    f32x4 v0 = *(const f32x4*)src;
    f32x4 v1 = *(const f32x4*)(src + 4);
    u32x4 w;
    w.x = (u32)f2b(v0.x) | ((u32)f2b(v0.y) << 16);
    w.y = (u32)f2b(v0.z) | ((u32)f2b(v0.w) << 16);
    w.z = (u32)f2b(v1.x) | ((u32)f2b(v1.y) << 16);
    w.w = (u32)f2b(v1.z) | ((u32)f2b(v1.w) << 16);
    *(u32x4*)(A + idx) = w;
}

// ---------------------------------------------------------------------------
// 2) W [2048][5120] f32 -> Wt [5120][2048] bf16, transposed + PRE-SWIZZLED
//    (same granule rule, keyed by n-row & 7).
// ---------------------------------------------------------------------------
__global__ __launch_bounds__(256) void convert_W(const float* __restrict__ W,
                                                 u16* __restrict__ Wt) {
    __shared__ float tile[64][33];      // [k][n]
    const int t  = threadIdx.x;
    const int tx = t & 31;              // n
    const int ty = t >> 5;              // 0..7 (k)
    const int n0 = blockIdx.x * 32;     // 160 blocks
    const int k0 = blockIdx.y * 64;     // 32 blocks
#pragma unroll
    for (int i = 0; i < 8; ++i)
        tile[ty + 8 * i][tx] = W[(size_t)(k0 + ty + 8 * i) * N_DIM + n0 + tx];
    __syncthreads();
    const int n = t >> 3;               // 0..31
    const int s = t & 7;                // output granule slot
    const int g = s ^ (n & 7);          // source granule ((n0+n)&7 == n&7)
    u32x4 w;
    w.x = (u32)f2b(tile[g * 8 + 0][n]) | ((u32)f2b(tile[g * 8 + 1][n]) << 16);
    w.y = (u32)f2b(tile[g * 8 + 2][n]) | ((u32)f2b(tile[g * 8 + 3][n]) << 16);
    w.z = (u32)f2b(tile[g * 8 + 4][n]) | ((u32)f2b(tile[g * 8 + 5][n]) << 16);
    w.w = (u32)f2b(tile[g * 8 + 6][n]) | ((u32)f2b(tile[g * 8 + 7][n]) << 16);
    *(u32x4*)(Wt + (size_t)(n0 + n) * K_DIM + k0 + s * 8) = w;
}

// ---------------------------------------------------------------------------
// 3) GEMM: 256x256, BK=64, 512 thr (8 waves 2Mx4N), 8-phase pipeline.
//    Units (16 KiB): A[s][h] = tile rows with bit6==h ({h*64..}u{128+h*64..});
//    B[s][h] = n-rows with bit5==h (4 stripes of 32). Each wave's phase (q,nh)
//    reads only A[s][q] and B[s][nh]. Local row: A u=(m*16+lr)|(wr<<6),
//    B u=(n*16+lr)|(wc<<5); swizzle key (globalrow&7)==(u&7)==lr&7.
// ---------------------------------------------------------------------------
#define BK 64

__device__ __forceinline__ void gld_lds16(const void* g, void* l) {
    __builtin_amdgcn_global_load_lds(
        (const __attribute__((address_space(1))) void*)g,
        (__attribute__((address_space(3))) void*)l, 16, 0, 0);
}

#define AU(s, h) ((s) * 16384 + (h) * 8192)            // u16 index of A unit
#define BU(s, h) (32768 + (s) * 16384 + (h) * 8192)    // u16 index of B unit

#define SBAR()  __builtin_amdgcn_sched_barrier(0)
#define BAR()   do { SBAR(); asm volatile("s_barrier" ::: "memory"); SBAR(); } while (0)
#define LGKM0() do { asm volatile("s_waitcnt lgkmcnt(0)" ::: "memory"); SBAR(); } while (0)
#define VM4()   asm volatile("s_waitcnt vmcnt(4)" ::: "memory")

__global__ __launch_bounds__(512, 2) void gemm_gates(const u16* __restrict__ A,
                                                     const u16* __restrict__ Bt,
                                                     const float* __restrict__ bias,
                                                     u16* __restrict__ gates) {
    __shared__ u16 lds[65536];            // 128 KiB

    const int t = threadIdx.x;
    // T1: bijective XCD swizzle (nwg = 1280, 1280 % 8 == 0)
    const int bid = blockIdx.x;
    const int swz = (bid & 7) * 160 + (bid >> 3);
    const int m0 = (swz & 63) << 8;       // 64 M-blocks
    const int n0 = (swz >> 6) << 8;       // 20 N-blocks

    const int l   = t & 63;
    const int wid = t >> 6;
    const int wr  = wid >> 2;             // 0/1  (M)
    const int wc  = wid & 3;              // 0..3 (N)
    const int lr  = l & 15;
    const int lh  = l >> 4;
    const int z   = lr & 7;
    const int sA0 = (lh ^ z) * 8;         // sk=0 granule slot offset (u16)

    // staging bases: thread t -> row t>>3, granule t&7 (global pre-swizzled)
    const int tb = t >> 3;                // 0..63
    const u16* aBase = A  + (size_t)(m0 + tb) * K_DIM + (t & 7) * 8;
    const u16* bBase = Bt + (size_t)(n0 + (tb & 31) + (tb >> 5) * 64) * K_DIM
                          + (t & 7) * 8;
    const int dOff = t * 8;               // u16

    f32x4 acc[8][4] = {};
    short8 af[4][2], bf0[2][2], bf1[2][2];

    // A[s][h] stripes: rows h*64+[0,64) and 128+h*64+[0,64)
#define STAGE_A(s, h, OFF) do {                                               \
    gld_lds16(aBase + (size_t)((h) * 64) * K_DIM + (OFF),                     \
              &lds[AU(s, h) + dOff]);                                         \
    gld_lds16(aBase + (size_t)((h) * 64 + 128) * K_DIM + (OFF),               \
              &lds[AU(s, h) + 4096 + dOff]);                                  \
} while (0)
    // B[s][h] stripes: base already has tlow + thi*64; + h*32, +128 for i=1
#define STAGE_B(s, h, OFF) do {                                               \
    gld_lds16(bBase + (size_t)((h) * 32) * K_DIM + (OFF),                     \
              &lds[BU(s, h) + dOff]);                                         \
    gld_lds16(bBase + (size_t)((h) * 32 + 128) * K_DIM + (OFF),               \
              &lds[BU(s, h) + 4096 + dOff]);                                  \
} while (0)

#define RD_AF(s, q) do {                                                      \
    _Pragma("unroll") for (int m = 0; m < 4; ++m) {                           \
        const int u_ = AU(s, q) + (wr * 64 + m * 16 + lr) * 64;               \
        af[m][0] = *(const short8*)&lds[u_ + sA0];                            \
        af[m][1] = *(const short8*)&lds[u_ + (sA0 ^ 32)];                     \
    }                                                                         \
} while (0)
#define RD_BF(dst, s, h) do {                                                 \
    _Pragma("unroll") for (int n = 0; n < 2; ++n) {                           \
        const int u_ = BU(s, h) + (wc * 32 + n * 16 + lr) * 64;               \
        dst[n][0] = *(const short8*)&lds[u_ + sA0];                           \
        dst[n][1] = *(const short8*)&lds[u_ + (sA0 ^ 32)];                    \
    }                                                                         \
} while (0)

#define MFMA16(q, nh, BF) do {                                                \
    __builtin_amdgcn_s_setprio(1);                                            \
    _Pragma("unroll") for (int sk = 0; sk < 2; ++sk)                          \
    _Pragma("unroll") for (int m = 0; m < 4; ++m)                             \
    _Pragma("unroll") for (int n = 0; n < 2; ++n)                             \
        acc[(q) * 4 + m][(nh) * 2 + n] =                                      \
            __builtin_amdgcn_mfma_f32_16x16x32_bf16(                          \
                af[m][sk], BF[n][sk], acc[(q) * 4 + m][(nh) * 2 + n], 0, 0, 0);\
    __builtin_amdgcn_s_setprio(0);                                            \
} while (0)

    // prologue: stage tile0 in FIFO order A0,B0,B1,A1; vmcnt(4) -> A0,B0 in.
    STAGE_A(0, 0, 0); STAGE_B(0, 0, 0); STAGE_B(0, 1, 0); STAGE_A(0, 1, 0);
    SBAR(); VM4(); BAR();

#pragma unroll 1
    for (int kt = 0; kt < 32; ++kt) {
        const int s  = kt & 1;
        const int sp = s ^ 1;
        const int OFF = (kt + 1) * BK;    // kt=31: benign in-ws OOB, never read
        // P1: needs A[s][0],B[s][0] (guarded by prev P4/prologue vmcnt(4))
        RD_AF(s, 0); RD_BF(bf0, s, 0); STAGE_A(sp, 0, OFF);
        BAR(); LGKM0(); MFMA16(0, 0, bf0);
        VM4();   // forces B1(kt) landed (outstanding <=4: A1(kt),A0(kt+1))
        BAR();
        // P2: needs B[s][1]
        RD_BF(bf1, s, 1); STAGE_B(sp, 0, OFF);
        BAR(); LGKM0(); MFMA16(0, 1, bf1);
        VM4();   // forces A1(kt) landed (<=4: A0(kt+1),B0(kt+1))
        BAR();
        // P3: needs A[s][1]
        RD_AF(s, 1); STAGE_B(sp, 1, OFF);
        BAR(); LGKM0(); MFMA16(1, 1, bf1);
        BAR();
        // P4: no new reads (af q1, bf0 live in regs)
        STAGE_A(sp, 1, OFF);
        BAR(); MFMA16(1, 0, bf0);
        VM4();   // forces A0(kt+1),B0(kt+1) landed (<=4: B1(kt+1),A1(kt+1))
        BAR();
    }
#undef STAGE_A
#undef STAGE_B
#undef RD_AF
#undef RD_BF
#undef MFMA16

    // epilogue: bias + activation (block's N-tile lies in one gate group)
    const int grp = n0 >> 10;             // 0..4 : f,i,o,c,m
#pragma unroll
    for (int ni = 0; ni < 4; ++ni) {
        int col = n0 + wc * 64 + ni * 16 + lr;
        float bv = bias[col];
#pragma unroll
        for (int q = 0; q < 2; ++q) {
#pragma unroll
            for (int m = 0; m < 4; ++m) {
#pragma unroll
                for (int j = 0; j < 4; ++j) {
                    int row = m0 + wr * 128 + q * 64 + m * 16 + lh * 4 + j;
                    float v = acc[q * 4 + m][ni][j] + bv;
                    float g = (grp == 3) ? tanh_fast(v) : sigm(v);
                    gates[(size_t)row * N_DIM + col] = f2b(g);
                }
            }
        }
    }
}

// ---------------------------------------------------------------------------
// 4) per-row: LN stats over o, cell update, outputs
// ---------------------------------------------------------------------------
__global__ __launch_bounds__(256) void fuse_out(const u16* __restrict__ gates,
                                                const float* __restrict__ c_prev,
                                                const float* __restrict__ ret,
                                                const float* __restrict__ gamma,
                                                const float* __restrict__ beta,
                                                float* __restrict__ out) {
    const int r = blockIdx.x;
    const int t = threadIdx.x;
    const u16* g = gates + (size_t)r * N_DIM;
    const int j0 = t * 4;

    // o = sigmoid(o_pre) already; LN stats over the row of 1024
    u16x4 ov = *(const u16x4*)(g + 2048 + j0);
    float o0 = b2f(ov.x), o1 = b2f(ov.y), o2 = b2f(ov.z), o3 = b2f(ov.w);
    float s1 = o0 + o1 + o2 + o3;
    float s2 = o0 * o0 + o1 * o1 + o2 * o2 + o3 * o3;
#pragma unroll
    for (int off = 32; off; off >>= 1) {
        s1 += __shfl_xor(s1, off, 64);
        s2 += __shfl_xor(s2, off, 64);
    }
    __shared__ float red[8];
    if ((t & 63) == 0) { red[t >> 6] = s1; red[4 + (t >> 6)] = s2; }
    __syncthreads();
    float S1 = red[0] + red[1] + red[2] + red[3];
    float S2 = red[4] + red[5] + red[6] + red[7];
    float mu   = S1 * (1.f / 1024.f);
    float var  = S2 * (1.f / 1024.f) - mu * mu;
    float rstd = rsqrtf(var + 1e-5f);

    u16x4 fv = *(const u16x4*)(g + j0);
    u16x4 iv = *(const u16x4*)(g + 1024 + j0);
    u16x4 cv = *(const u16x4*)(g + 3072 + j0);
    u16x4 mv = *(const u16x4*)(g + 4096 + j0);
    f32x4 cp = *(const f32x4*)(c_prev + (size_t)r * H_DIM + j0);
    f32x4 rt = *(const f32x4*)(ret + j0);
    f32x4 gm = *(const f32x4*)(gamma + j0);
    f32x4 bt = *(const f32x4*)(beta + j0);

    float of[4] = {o0, o1, o2, o3};
    u16 fa[4] = {fv.x, fv.y, fv.z, fv.w};
    u16 ia[4] = {iv.x, iv.y, iv.z, iv.w};
    u16 ca[4] = {cv.x, cv.y, cv.z, cv.w};
    u16 ma[4] = {mv.x, mv.y, mv.z, mv.w};

    f32x4 hout, cout;
#pragma unroll
    for (int i = 0; i < 4; ++i) {
        float f = b2f(fa[i]), ig = b2f(ia[i]), cc = b2f(ca[i]), m = b2f(ma[i]);
        float cpv = cp[i], rv = rt[i];
        float c1 = f * cpv + ig * cc;
        float c2 = c1 * rv + (1.f - rv) * cpv;
        float cn = m * c2 + (1.f - m) * cpv;
        float ln = (of[i] - mu) * rstd * gm[i] + bt[i];
        float oe = sigm(ln);
        float hn = oe * tanh_fast(cn);
        hout[i] = hn;
        cout[i] = cn;
    }
    *(f32x4*)(out + (size_t)r * H_DIM + j0) = hout;
    *(f32x4*)(out + (size_t)B_ROWS * H_DIM + (size_t)r * H_DIM + j0) = cout;
}

// ---------------------------------------------------------------------------
extern "C" void kernel_launch(void* const* d_in, const int* in_sizes, int n_in,
                              void* d_out, int out_size, void* d_ws, size_t ws_size,
                              hipStream_t stream) {
    const float* x      = (const float*)d_in[0];
    const float* h_prev = (const float*)d_in[1];
    const float* c_prev = (const float*)d_in[2];
    const float* W      = (const float*)d_in[3];
    const float* bias   = (const float*)d_in[4];
    const float* gamma  = (const float*)d_in[5];
    const float* beta   = (const float*)d_in[6];
    const float* ret    = (const float*)d_in[7];
    float* out = (float*)d_out;

    u16* Abuf  = (u16*)d_ws;                             // [16384][2048]
    u16* Wt    = Abuf + (size_t)B_ROWS * K_DIM;          // [5120][2048]
    u16* gates = Wt + (size_t)N_DIM * K_DIM;             // [16384][5120]

    convert_A<<<(B_ROWS * K_DIM / 8) / 256, 256, 0, stream>>>(x, h_prev, Abuf);
    convert_W<<<dim3(N_DIM / 32, K_DIM / 64), 256, 0, stream>>>(W, Wt);
    gemm_gates<<<(B_ROWS / 256) * (N_DIM / 256), 512, 0, stream>>>(Abuf, Wt, bias, gates);
    fuse_out<<<B_ROWS, 256, 0, stream>>>(gates, c_prev, ret, gamma, beta, out);
}